// Round 17
// baseline (552.220 us; speedup 1.0000x reference)
//
#include <hip/hip_runtime.h>
#include <hip/hip_bf16.h>

#define HID 50
#define LAT 16
#define NW  4          // waves per block (independent after one-time dt staging)
#define BLK (NW * 64)
#define MPW 16         // batch elements per wave (one MFMA M-tile)
#define LOG2E2 2.8853900817779268f   // 2*log2(e), folded into ODE layer-1 weights

typedef __attribute__((ext_vector_type(8))) short short8;   // 8 bf16 = 4 VGPRs
typedef __attribute__((ext_vector_type(4))) float f32x4;
typedef __attribute__((ext_vector_type(4))) unsigned uint4v;

#define MFMA16(a, b, c) __builtin_amdgcn_mfma_f32_16x16x32_bf16(a, b, c, 0, 0, 0)

// pack two fp32 -> dword of 2 bf16 (RNE); lowers to one v_cvt_pk_bf16_f32.
__device__ __forceinline__ unsigned pkbf(float lo, float hi) {
    __hip_bfloat162 h = __float22bfloat162_rn(float2{lo, hi});
    unsigned r;
    __builtin_memcpy(&r, &h, 4);
    return r;
}

// kappa-label -> hidden-unit map (R15 repack).  Tiles 0-2 hold real units
// 0..47; tile 3 holds units 48,49 at m=0,1 (q=0), the bias/sat slot at
// kappa==38 (m=2, q=0), everything else dead.  odef/decode evaluate the
// activation on 14 lane-values instead of 16; the sat slot is the constant
// biasdw dword (no tanh eval).
__device__ __forceinline__ int unitmap(int k, bool& dead, bool& sat) {
    dead = false; sat = false;
    int u = k;
    if (k == 36)                          u = 48;
    else if (k == 37)                     u = 49;
    else if (k == 38)                     sat = true;
    else if (k == 39)                     dead = true;
    else if (k >= 44 && k < 48)           dead = true;
    else if ((k >= 48 && k < 52) || (k >= 56 && k < 60)) u = k - 12;
    else if (k >= 52 && k < 56)           dead = true;
    else if (k >= 60)                     dead = true;
    return u;   // k<36 (not 36-39) and 40-43: identity
}

// ---- A-frag builders (weights as MFMA A-operand; one-time setup) ----
// Layer-1: A-row m of tile ti holds unit unitmap(kappa(ti,m)),
// kappa(ti,m)=32*(ti>>1)+8*(m>>2)+4*(ti&1)+(m&3) -- CD regs land exactly on
// GEMM2 B-frag slots.  k-slot (q,j): j<4 -> input row 4q+j; (q==0,j==4) ->
// bias*scale.  sat/dead columns all-zero (bias enters via GEMM2 B const).
__device__ __forceinline__ short8 afrag1(const float* __restrict__ W, const float* __restrict__ bias,
                                         int Kreal, int ti, int q, int m, float scale) {
    int kap = 32 * (ti >> 1) + 8 * (m >> 2) + 4 * (ti & 1) + (m & 3);
    bool dead, sat;
    int u = unitmap(kap, dead, sat);
    float e[8];
#pragma unroll
    for (int j = 0; j < 8; j++) {
        float f = 0.0f;
        if (!dead && !sat) {
            if (j < 4) {
                int row = 4 * q + j;
                if (row < Kreal) f = W[row * HID + u] * scale;
            } else if (j == 4 && q == 0) f = bias[u] * scale;
        }
        e[j] = f;
    }
    uint4v d;
#pragma unroll
    for (int p = 0; p < 4; p++) d[p] = pkbf(e[2 * p], e[2 * p + 1]);
    return __builtin_bit_cast(short8, d);
}

// Layer-2: A2[m][kap] = W2[unit(kap)][m]; kappa==38 (sat slot) -> bias row b2[m].
__device__ __forceinline__ short8 afrag2(const float* __restrict__ W2, const float* __restrict__ b2,
                                         int N2, int chunk, int q, int m) {
    float e[8];
#pragma unroll
    for (int j = 0; j < 8; j++) {
        int kap = 32 * chunk + 8 * q + j;
        bool dead, sat;
        int u = unitmap(kap, dead, sat);
        float f = 0.0f;
        if (m < N2) {
            if (sat)       f = b2[m];
            else if (!dead) f = W2[u * N2 + m];
        }
        e[j] = f;
    }
    uint4v d;
#pragma unroll
    for (int p = 0; p < 4; p++) d[p] = pkbf(e[2 * p], e[2 * p + 1]);
    return __builtin_bit_cast(short8, d);
}

__global__ void __attribute__((amdgpu_flat_work_group_size(BLK, BLK), amdgpu_waves_per_eu(4, 4)))
node_kernel(const float* __restrict__ x0, const float* __restrict__ tt,
            const float* __restrict__ We1, const float* __restrict__ be1,
            const float* __restrict__ We2, const float* __restrict__ be2,
            const float* __restrict__ Wo1, const float* __restrict__ bo1,
            const float* __restrict__ Wo2, const float* __restrict__ bo2,
            const float* __restrict__ Wd1, const float* __restrict__ bd1,
            const float* __restrict__ Wd2, const float* __restrict__ bd2,
            float* __restrict__ out, int B, int T) {
    __shared__ float sdt[128];   // dt table (lgkm-side; loop stays vmcnt-free)
    {
        int idx = threadIdx.x;
        if (idx < T - 1) sdt[idx] = tt[idx + 1] - tt[idx];
    }
    __syncthreads();   // one-time; waves independent afterwards

    const int lane = threadIdx.x & 63;
    const int q    = lane >> 4;          // quad
    const int c    = lane & 15;          // batch col in B/CD frags; row m in A frags
    const int wid  = threadIdx.x >> 6;
    const int wbase = blockIdx.x * (NW * MPW) + wid * MPW;

    const f32x4 zero4 = {0.0f, 0.0f, 0.0f, 0.0f};
    // bf16(1.0) low half for q==0 lanes: serves the z-frag bias slot (k=4)
    // and the chunk-1 sat slot (kappa 38).
    const unsigned biasdw = (q == 0) ? 0x3F80u : 0u;

    // ---- persistent weight A-frags (unified VGPR/AGPR file; whole kernel) ----
    short8 A1o[4], A1d[4], A2o[2], A2d[2];
#pragma unroll
    for (int ti = 0; ti < 4; ti++) {
        A1o[ti] = afrag1(Wo1, bo1, LAT, ti, q, c, LOG2E2);
        A1d[ti] = afrag1(Wd1, bd1, LAT, ti, q, c, 1.0f);
    }
#pragma unroll
    for (int ch = 0; ch < 2; ch++) {
        A2o[ch] = afrag2(Wo2, bo2, LAT, ch, q, c);
        A2d[ch] = afrag2(Wd2, bd2, 1, ch, q, c);
    }

    // ---- Encoder (transient frags), repacked layout, relu on 14 values ----
    f32x4 z;
    {
        uint4v bx = {0u, 0u, 0u, 0u};
        if (q == 0) {  // x at k=0,1; bias 1.0 at k=4
            bx[0] = pkbf(x0[2 * (wbase + c)], x0[2 * (wbase + c) + 1]);
            bx[2] = 0x3F80u;
        }
        short8 Bx = __builtin_bit_cast(short8, bx);
        f32x4 h0 = MFMA16(afrag1(We1, be1, 2, 0, q, c, 1.0f), Bx, zero4);
        f32x4 h1 = MFMA16(afrag1(We1, be1, 2, 1, q, c, 1.0f), Bx, zero4);
        f32x4 h2 = MFMA16(afrag1(We1, be1, 2, 2, q, c, 1.0f), Bx, zero4);
        f32x4 h3 = MFMA16(afrag1(We1, be1, 2, 3, q, c, 1.0f), Bx, zero4);
        uint4v d0 = {pkbf(fmaxf(h0[0], 0.f), fmaxf(h0[1], 0.f)), pkbf(fmaxf(h0[2], 0.f), fmaxf(h0[3], 0.f)),
                     pkbf(fmaxf(h1[0], 0.f), fmaxf(h1[1], 0.f)), pkbf(fmaxf(h1[2], 0.f), fmaxf(h1[3], 0.f))};
        uint4v d1 = {pkbf(fmaxf(h2[0], 0.f), fmaxf(h2[1], 0.f)), pkbf(fmaxf(h2[2], 0.f), fmaxf(h2[3], 0.f)),
                     pkbf(fmaxf(h3[0], 0.f), fmaxf(h3[1], 0.f)), biasdw};
        z = MFMA16(afrag2(We2, be2, 16, 1, q, c), __builtin_bit_cast(short8, d1),
            MFMA16(afrag2(We2, be2, 16, 0, q, c), __builtin_bit_cast(short8, d0), zero4));
    }

    // z (CD layout: lat 4q+r, batch c) -> GEMM1 B-frag: k(j<4)=lat 4q+j, bias at k=4
    auto mkzfrag = [&](f32x4 zz) -> short8 {
        uint4v d = {pkbf(zz[0], zz[1]), pkbf(zz[2], zz[3]), biasdw, 0u};
        return __builtin_bit_cast(short8, d);
    };

    // ODE func: 6 MFMA + 14-wide STAGED tanh, reciprocal via magic-init +
    // 2 Newton (all full-rate VALU; only 1 trans (exp2) per value).
    // tanh = 1 - 2/(1+2^s), s pre-scaled by 2*log2(e) in A1o.  If trans is
    // quarter-rate (~16cy) this is -6cy/tanh vs rcp form; staging keeps the
    // 14 Newton chains pipelined (R9's serial-chain failure mode removed).
    // Magic path proven on this data in R9 (passed, absmax 0.0625);
    // y in [1, 2^40] is well inside the magic constant's valid range.
    auto odef = [&](short8 zf) -> f32x4 {
        f32x4 h0 = MFMA16(A1o[0], zf, zero4);
        f32x4 h1 = MFMA16(A1o[1], zf, zero4);
        f32x4 h2 = MFMA16(A1o[2], zf, zero4);
        f32x4 h3 = MFMA16(A1o[3], zf, zero4);
        float hv[14] = {h0[0], h0[1], h0[2], h0[3], h1[0], h1[1], h1[2], h1[3],
                        h2[0], h2[1], h2[2], h2[3], h3[0], h3[1]};
        float e[14], y[14], r[14], u[14], t[14];
#pragma unroll
        for (int i = 0; i < 14; i++) e[i] = __builtin_amdgcn_exp2f(hv[i]);
        __builtin_amdgcn_sched_barrier(0);
#pragma unroll
        for (int i = 0; i < 14; i++) y[i] = e[i] + 1.0f;
        __builtin_amdgcn_sched_barrier(0);
#pragma unroll
        for (int i = 0; i < 14; i++)
            r[i] = __builtin_bit_cast(float, 0x7EF311C3u - __builtin_bit_cast(unsigned, y[i]));
        __builtin_amdgcn_sched_barrier(0);
#pragma unroll
        for (int i = 0; i < 14; i++) u[i] = __builtin_fmaf(-y[i], r[i], 2.0f);
        __builtin_amdgcn_sched_barrier(0);
#pragma unroll
        for (int i = 0; i < 14; i++) r[i] = r[i] * u[i];
        __builtin_amdgcn_sched_barrier(0);
#pragma unroll
        for (int i = 0; i < 14; i++) u[i] = __builtin_fmaf(-y[i], r[i], 2.0f);
        __builtin_amdgcn_sched_barrier(0);
#pragma unroll
        for (int i = 0; i < 14; i++) r[i] = r[i] * u[i];
        __builtin_amdgcn_sched_barrier(0);
#pragma unroll
        for (int i = 0; i < 14; i++) t[i] = __builtin_fmaf(-2.0f, r[i], 1.0f);
        uint4v d0 = {pkbf(t[0], t[1]), pkbf(t[2], t[3]), pkbf(t[4], t[5]), pkbf(t[6], t[7])};
        uint4v d1 = {pkbf(t[8], t[9]), pkbf(t[10], t[11]), pkbf(t[12], t[13]), biasdw};
        return MFMA16(A2o[1], __builtin_bit_cast(short8, d1),
               MFMA16(A2o[0], __builtin_bit_cast(short8, d0), zero4));
    };

    // decoder: relu on 14 values; y[c] lands in reg0 of q==0 lanes
    auto decode = [&](short8 zf) -> f32x4 {
        f32x4 h0 = MFMA16(A1d[0], zf, zero4);
        f32x4 h1 = MFMA16(A1d[1], zf, zero4);
        f32x4 h2 = MFMA16(A1d[2], zf, zero4);
        f32x4 h3 = MFMA16(A1d[3], zf, zero4);
        uint4v d0 = {pkbf(fmaxf(h0[0], 0.f), fmaxf(h0[1], 0.f)), pkbf(fmaxf(h0[2], 0.f), fmaxf(h0[3], 0.f)),
                     pkbf(fmaxf(h1[0], 0.f), fmaxf(h1[1], 0.f)), pkbf(fmaxf(h1[2], 0.f), fmaxf(h1[3], 0.f))};
        uint4v d1 = {pkbf(fmaxf(h2[0], 0.f), fmaxf(h2[1], 0.f)), pkbf(fmaxf(h2[2], 0.f), fmaxf(h2[3], 0.f)),
                     pkbf(fmaxf(h3[0], 0.f), fmaxf(h3[1], 0.f)), biasdw};
        return MFMA16(A2d[1], __builtin_bit_cast(short8, d1),
               MFMA16(A2d[0], __builtin_bit_cast(short8, d0), zero4));
    };

    // ---- main time loop: register dataflow; only VMEM op is the out store ----
    for (int s = 0;; s++) {
        float dt = sdt[s];
        short8 zf = mkzfrag(z);
        f32x4 y = decode(zf);
        if (lane < 16) out[(size_t)s * B + wbase + c] = y[0];

        if (s == T - 1) break;

        f32x4 k = odef(zf);                          // k1 (shares zf with decode)
        f32x4 ksum = k;
        f32x4 ztmp = z + (0.5f * dt) * k;
        k = odef(mkzfrag(ztmp));                     // k2
        ksum += 2.0f * k;
        ztmp = z + (0.5f * dt) * k;
        k = odef(mkzfrag(ztmp));                     // k3
        ksum += 2.0f * k;
        ztmp = z + dt * k;
        k = odef(mkzfrag(ztmp));                     // k4
        z = z + (dt * (1.0f / 6.0f)) * (ksum + k);
    }
}

extern "C" void kernel_launch(void* const* d_in, const int* in_sizes, int n_in,
                              void* d_out, int out_size, void* d_ws, size_t ws_size,
                              hipStream_t stream) {
    const float* x0  = (const float*)d_in[0];
    const float* t   = (const float*)d_in[1];
    const float* We1 = (const float*)d_in[2];
    const float* be1 = (const float*)d_in[3];
    const float* We2 = (const float*)d_in[4];
    const float* be2 = (const float*)d_in[5];
    const float* Wo1 = (const float*)d_in[6];
    const float* bo1 = (const float*)d_in[7];
    const float* Wo2 = (const float*)d_in[8];
    const float* bo2 = (const float*)d_in[9];
    const float* Wd1 = (const float*)d_in[10];
    const float* bd1 = (const float*)d_in[11];
    const float* Wd2 = (const float*)d_in[12];
    const float* bd2 = (const float*)d_in[13];
    float* out = (float*)d_out;

    int B = in_sizes[0] / 2;   // 65536
    int T = in_sizes[1];       // 100

    dim3 block(BLK);
    dim3 grid(B / (NW * MPW)); // 1024 blocks, 4 waves each
    hipLaunchKernelGGL(node_kernel, grid, block, 0, stream,
                       x0, t, We1, be1, We2, be2, Wo1, bo1, Wo2, bo2,
                       Wd1, bd1, Wd2, bd2, out, B, T);
}

// Round 18
// 473.310 us; speedup vs baseline: 1.1667x; 1.1667x over previous
//
#include <hip/hip_runtime.h>
#include <hip/hip_fp16.h>

#define HID 50
#define LAT 16
#define NW  4          // waves per block (independent after one-time dt staging)
#define BLK (NW * 64)
#define MPW 16         // batch elements per wave (one MFMA M-tile)
#define LOG2E2 2.8853900817779268f   // 2*log2(e), folded into ODE layer-1 weights

typedef __attribute__((ext_vector_type(8))) _Float16 half8v;  // 8 f16 = 4 VGPRs
typedef __attribute__((ext_vector_type(4))) float f32x4;
typedef __attribute__((ext_vector_type(4))) unsigned uint4v;

#define MFMAH(a, b, c) __builtin_amdgcn_mfma_f32_16x16x32_f16(a, b, c, 0, 0, 0)

// pack two fp32 -> dword of 2 f16 (v_cvt_pkrtz_f16_f32, 1 instr)
__device__ __forceinline__ unsigned pkhf(float lo, float hi) {
    __half2 h = __float22half2_rn(float2{lo, hi});
    unsigned r;
    __builtin_memcpy(&r, &h, 4);
    return r;
}
__device__ __forceinline__ unsigned h2u(__half2 h) {
    unsigned r;
    __builtin_memcpy(&r, &h, 4);
    return r;
}

// kappa-label -> hidden-unit map (R15 repack).  Tiles 0-2 hold real units
// 0..47; tile 3 holds units 48,49 at m=0,1 (q=0), the bias/sat slot at
// kappa==38 (m=2, q=0), everything else dead.  odef/decode evaluate the
// activation on 14 lane-values; the sat slot is the constant biasdw dword.
__device__ __forceinline__ int unitmap(int k, bool& dead, bool& sat) {
    dead = false; sat = false;
    int u = k;
    if (k == 36)                          u = 48;
    else if (k == 37)                     u = 49;
    else if (k == 38)                     sat = true;
    else if (k == 39)                     dead = true;
    else if (k >= 44 && k < 48)           dead = true;
    else if ((k >= 48 && k < 52) || (k >= 56 && k < 60)) u = k - 12;
    else if (k >= 52 && k < 56)           dead = true;
    else if (k >= 60)                     dead = true;
    return u;   // k<36 (not 36-39) and 40-43: identity
}

// ---- A-frag builders (weights as f16 MFMA A-operand; one-time setup) ----
// Layer-1: A-row m of tile ti holds unit unitmap(kappa(ti,m)),
// kappa(ti,m)=32*(ti>>1)+8*(m>>2)+4*(ti&1)+(m&3) -- CD regs land exactly on
// GEMM2 B-frag slots.  k-slot (q,j): j<4 -> input row 4q+j; (q==0,j==4) ->
// bias*scale.  sat/dead columns all-zero (bias enters via GEMM2 B const).
__device__ __forceinline__ half8v afrag1(const float* __restrict__ W, const float* __restrict__ bias,
                                         int Kreal, int ti, int q, int m, float scale) {
    int kap = 32 * (ti >> 1) + 8 * (m >> 2) + 4 * (ti & 1) + (m & 3);
    bool dead, sat;
    int u = unitmap(kap, dead, sat);
    float e[8];
#pragma unroll
    for (int j = 0; j < 8; j++) {
        float f = 0.0f;
        if (!dead && !sat) {
            if (j < 4) {
                int row = 4 * q + j;
                if (row < Kreal) f = W[row * HID + u] * scale;
            } else if (j == 4 && q == 0) f = bias[u] * scale;
        }
        e[j] = f;
    }
    uint4v d;
#pragma unroll
    for (int p = 0; p < 4; p++) d[p] = pkhf(e[2 * p], e[2 * p + 1]);
    return __builtin_bit_cast(half8v, d);
}

// Layer-2: A2[m][kap] = W2[unit(kap)][m]; kappa==38 (sat slot) -> bias row b2[m].
__device__ __forceinline__ half8v afrag2(const float* __restrict__ W2, const float* __restrict__ b2,
                                         int N2, int chunk, int q, int m) {
    float e[8];
#pragma unroll
    for (int j = 0; j < 8; j++) {
        int kap = 32 * chunk + 8 * q + j;
        bool dead, sat;
        int u = unitmap(kap, dead, sat);
        float f = 0.0f;
        if (m < N2) {
            if (sat)       f = b2[m];
            else if (!dead) f = W2[u * N2 + m];
        }
        e[j] = f;
    }
    uint4v d;
#pragma unroll
    for (int p = 0; p < 4; p++) d[p] = pkhf(e[2 * p], e[2 * p + 1]);
    return __builtin_bit_cast(half8v, d);
}

__global__ void __attribute__((amdgpu_flat_work_group_size(BLK, BLK), amdgpu_waves_per_eu(4, 4)))
node_kernel(const float* __restrict__ x0, const float* __restrict__ tt,
            const float* __restrict__ We1, const float* __restrict__ be1,
            const float* __restrict__ We2, const float* __restrict__ be2,
            const float* __restrict__ Wo1, const float* __restrict__ bo1,
            const float* __restrict__ Wo2, const float* __restrict__ bo2,
            const float* __restrict__ Wd1, const float* __restrict__ bd1,
            const float* __restrict__ Wd2, const float* __restrict__ bd2,
            float* __restrict__ out, int B, int T) {
    __shared__ float sdt[128];   // dt table (lgkm-side; loop stays vmcnt-free)
    {
        int idx = threadIdx.x;
        if (idx < T - 1) sdt[idx] = tt[idx + 1] - tt[idx];
    }
    __syncthreads();   // one-time; waves independent afterwards

    const int lane = threadIdx.x & 63;
    const int q    = lane >> 4;          // quad
    const int c    = lane & 15;          // batch col in B/CD frags; row m in A frags
    const int wid  = threadIdx.x >> 6;
    const int wbase = blockIdx.x * (NW * MPW) + wid * MPW;

    const f32x4 zero4 = {0.0f, 0.0f, 0.0f, 0.0f};
    // f16(1.0)=0x3C00 low half for q==0 lanes: z-frag bias slot (k=4) and the
    // chunk-1 sat slot (kappa 38).
    const unsigned biasdw = (q == 0) ? 0x3C00u : 0u;
    const __half2 one2 = __float2half2_rn(1.0f);
    const __half2 m22  = __float2half2_rn(-2.0f);

    // ---- persistent weight A-frags (f16; whole kernel) ----
    half8v A1o[4], A1d[4], A2o[2], A2d[2];
#pragma unroll
    for (int ti = 0; ti < 4; ti++) {
        A1o[ti] = afrag1(Wo1, bo1, LAT, ti, q, c, LOG2E2);
        A1d[ti] = afrag1(Wd1, bd1, LAT, ti, q, c, 1.0f);
    }
#pragma unroll
    for (int ch = 0; ch < 2; ch++) {
        A2o[ch] = afrag2(Wo2, bo2, LAT, ch, q, c);
        A2d[ch] = afrag2(Wd2, bd2, 1, ch, q, c);
    }

    // ---- Encoder (transient f16 frags), relu in f32 then pack ----
    f32x4 z;
    {
        uint4v bx = {0u, 0u, 0u, 0u};
        if (q == 0) {  // x at k=0,1; bias 1.0 at k=4
            bx[0] = pkhf(x0[2 * (wbase + c)], x0[2 * (wbase + c) + 1]);
            bx[2] = 0x3C00u;
        }
        half8v Bx = __builtin_bit_cast(half8v, bx);
        f32x4 h0 = MFMAH(afrag1(We1, be1, 2, 0, q, c, 1.0f), Bx, zero4);
        f32x4 h1 = MFMAH(afrag1(We1, be1, 2, 1, q, c, 1.0f), Bx, zero4);
        f32x4 h2 = MFMAH(afrag1(We1, be1, 2, 2, q, c, 1.0f), Bx, zero4);
        f32x4 h3 = MFMAH(afrag1(We1, be1, 2, 3, q, c, 1.0f), Bx, zero4);
        uint4v d0 = {pkhf(fmaxf(h0[0], 0.f), fmaxf(h0[1], 0.f)), pkhf(fmaxf(h0[2], 0.f), fmaxf(h0[3], 0.f)),
                     pkhf(fmaxf(h1[0], 0.f), fmaxf(h1[1], 0.f)), pkhf(fmaxf(h1[2], 0.f), fmaxf(h1[3], 0.f))};
        uint4v d1 = {pkhf(fmaxf(h2[0], 0.f), fmaxf(h2[1], 0.f)), pkhf(fmaxf(h2[2], 0.f), fmaxf(h2[3], 0.f)),
                     pkhf(fmaxf(h3[0], 0.f), fmaxf(h3[1], 0.f)), biasdw};
        z = MFMAH(afrag2(We2, be2, 16, 1, q, c), __builtin_bit_cast(half8v, d1),
            MFMAH(afrag2(We2, be2, 16, 0, q, c), __builtin_bit_cast(half8v, d0), zero4));
    }

    // z (CD layout: lat 4q+r, batch c) -> GEMM1 B-frag: k(j<4)=lat 4q+j, bias at k=4
    auto mkzfrag = [&](f32x4 zz) -> half8v {
        uint4v d = {pkhf(zz[0], zz[1]), pkhf(zz[2], zz[3]), biasdw, 0u};
        return __builtin_bit_cast(half8v, d);
    };

    // ODE func: 6 MFMA + packed-f16 tanh on 7 half2 pairs (14 values).
    // tanh = 1 - 2/(1+2^s), s pre-scaled by 2*log2(e) in A1o.  f16 overflow
    // (s>16 -> inf -> rcp 0 -> t=1) IS the correct saturation.  Packed ops
    // halve the add/fma/pack count vs the f32 path (R18: instruction diet is
    // the only lever that has ever moved this kernel).
    auto odef = [&](half8v zf) -> f32x4 {
        f32x4 h0 = MFMAH(A1o[0], zf, zero4);
        f32x4 h1 = MFMAH(A1o[1], zf, zero4);
        f32x4 h2 = MFMAH(A1o[2], zf, zero4);
        f32x4 h3 = MFMAH(A1o[3], zf, zero4);
        __half2 p[7], e[7], y[7], r[7], t[7];
        p[0] = __float22half2_rn(float2{h0[0], h0[1]});
        p[1] = __float22half2_rn(float2{h0[2], h0[3]});
        p[2] = __float22half2_rn(float2{h1[0], h1[1]});
        p[3] = __float22half2_rn(float2{h1[2], h1[3]});
        p[4] = __float22half2_rn(float2{h2[0], h2[1]});
        p[5] = __float22half2_rn(float2{h2[2], h2[3]});
        p[6] = __float22half2_rn(float2{h3[0], h3[1]});
        __builtin_amdgcn_sched_barrier(0);
#pragma unroll
        for (int i = 0; i < 7; i++) e[i] = h2exp2(p[i]);
        __builtin_amdgcn_sched_barrier(0);
#pragma unroll
        for (int i = 0; i < 7; i++) y[i] = __hadd2(e[i], one2);
        __builtin_amdgcn_sched_barrier(0);
#pragma unroll
        for (int i = 0; i < 7; i++) r[i] = h2rcp(y[i]);
        __builtin_amdgcn_sched_barrier(0);
#pragma unroll
        for (int i = 0; i < 7; i++) t[i] = __hfma2(m22, r[i], one2);
        uint4v d0 = {h2u(t[0]), h2u(t[1]), h2u(t[2]), h2u(t[3])};
        uint4v d1 = {h2u(t[4]), h2u(t[5]), h2u(t[6]), biasdw};
        return MFMAH(A2o[1], __builtin_bit_cast(half8v, d1),
               MFMAH(A2o[0], __builtin_bit_cast(half8v, d0), zero4));
    };

    // decoder: relu in f32 (full-rate), pack pairs; y[c] in reg0 of q==0 lanes
    auto decode = [&](half8v zf) -> f32x4 {
        f32x4 h0 = MFMAH(A1d[0], zf, zero4);
        f32x4 h1 = MFMAH(A1d[1], zf, zero4);
        f32x4 h2 = MFMAH(A1d[2], zf, zero4);
        f32x4 h3 = MFMAH(A1d[3], zf, zero4);
        uint4v d0 = {pkhf(fmaxf(h0[0], 0.f), fmaxf(h0[1], 0.f)), pkhf(fmaxf(h0[2], 0.f), fmaxf(h0[3], 0.f)),
                     pkhf(fmaxf(h1[0], 0.f), fmaxf(h1[1], 0.f)), pkhf(fmaxf(h1[2], 0.f), fmaxf(h1[3], 0.f))};
        uint4v d1 = {pkhf(fmaxf(h2[0], 0.f), fmaxf(h2[1], 0.f)), pkhf(fmaxf(h2[2], 0.f), fmaxf(h2[3], 0.f)),
                     pkhf(fmaxf(h3[0], 0.f), fmaxf(h3[1], 0.f)), biasdw};
        return MFMAH(A2d[1], __builtin_bit_cast(half8v, d1),
               MFMAH(A2d[0], __builtin_bit_cast(half8v, d0), zero4));
    };

    // ---- main time loop: register dataflow; only VMEM op is the out store ----
    for (int s = 0;; s++) {
        float dt = sdt[s];
        half8v zf = mkzfrag(z);
        f32x4 y = decode(zf);
        if (lane < 16) out[(size_t)s * B + wbase + c] = y[0];

        if (s == T - 1) break;

        f32x4 k = odef(zf);                          // k1 (shares zf with decode)
        f32x4 ksum = k;
        f32x4 ztmp = z + (0.5f * dt) * k;
        k = odef(mkzfrag(ztmp));                     // k2
        ksum += 2.0f * k;
        ztmp = z + (0.5f * dt) * k;
        k = odef(mkzfrag(ztmp));                     // k3
        ksum += 2.0f * k;
        ztmp = z + dt * k;
        k = odef(mkzfrag(ztmp));                     // k4
        z = z + (dt * (1.0f / 6.0f)) * (ksum + k);
    }
}

extern "C" void kernel_launch(void* const* d_in, const int* in_sizes, int n_in,
                              void* d_out, int out_size, void* d_ws, size_t ws_size,
                              hipStream_t stream) {
    const float* x0  = (const float*)d_in[0];
    const float* t   = (const float*)d_in[1];
    const float* We1 = (const float*)d_in[2];
    const float* be1 = (const float*)d_in[3];
    const float* We2 = (const float*)d_in[4];
    const float* be2 = (const float*)d_in[5];
    const float* Wo1 = (const float*)d_in[6];
    const float* bo1 = (const float*)d_in[7];
    const float* Wo2 = (const float*)d_in[8];
    const float* bo2 = (const float*)d_in[9];
    const float* Wd1 = (const float*)d_in[10];
    const float* bd1 = (const float*)d_in[11];
    const float* Wd2 = (const float*)d_in[12];
    const float* bd2 = (const float*)d_in[13];
    float* out = (float*)d_out;

    int B = in_sizes[0] / 2;   // 65536
    int T = in_sizes[1];       // 100

    dim3 block(BLK);
    dim3 grid(B / (NW * MPW)); // 1024 blocks, 4 waves each
    hipLaunchKernelGGL(node_kernel, grid, block, 0, stream,
                       x0, t, We1, be1, We2, be2, Wo1, bo1, Wo2, bo2,
                       Wd1, bd1, Wd2, bd2, out, B, T);
}